// Round 4
// baseline (740.532 us; speedup 1.0000x reference)
//
#include <hip/hip_runtime.h>

#define N_OPE 2048
#define N_MAC 1024
#define DIM   64
#define KOUT  128
#define NB    32

typedef __attribute__((ext_vector_type(8))) short short8;
typedef __attribute__((ext_vector_type(4))) float floatx4;

static __device__ __forceinline__ unsigned short f2bf(float f) {
    unsigned int u = __builtin_bit_cast(unsigned int, f);
    u += 0x7fffu + ((u >> 16) & 1u);   // round-to-nearest-even
    return (unsigned short)(u >> 16);
}
static __device__ __forceinline__ float bf2f(unsigned short h) {
    unsigned int u = ((unsigned int)h) << 16;
    return __builtin_bit_cast(float, u);
}

// ---------------- kernel 0: wa[d] = sum_n mac_w[n][d] * mac_alpha[n] ----------------
__global__ void k_wa(const float* __restrict__ mw, const float* __restrict__ ma,
                     float* __restrict__ wa)
{
    int d = threadIdx.x;                       // 64 threads
    float s = 0.f;
    #pragma unroll 8
    for (int n = 0; n < KOUT; ++n) s = fmaf(mw[n * DIM + d], ma[n], s);
    wa[d] = s;
}

// ---------------- kernel 1: h_ope via 3-term bf16 MFMA -> h_t (transposed bf16),
//                  plus pq[o] = (exp(attn_ope), exp(0.2*attn_ope)) from exact C.alpha ----
__global__ __launch_bounds__(256, 2) void k_ope(const float* __restrict__ feat,
        const float* __restrict__ w, const float* __restrict__ alpha,
        unsigned short* __restrict__ h_t, float2* __restrict__ pq)
{
    int wid = threadIdx.x >> 6, lane = threadIdx.x & 63;
    int L = lane & 15, q = lane >> 4;
    int base = blockIdx.x * 128 + wid * 32;           // row base for this wave
    int b = base >> 11;                                // rows per batch = 2048
    int o0w = base & (N_OPE - 1);

    float fA[2][2][8];                                 // [mf][ks][j]
    #pragma unroll
    for (int mf = 0; mf < 2; ++mf) {
        const float* fr = feat + (size_t)(base + mf * 16 + L) * DIM + q * 8;
        #pragma unroll
        for (int ks = 0; ks < 2; ++ks) {
            float4 v0 = *(const float4*)(fr + ks * 32);
            float4 v1 = *(const float4*)(fr + ks * 32 + 4);
            fA[mf][ks][0] = v0.x; fA[mf][ks][1] = v0.y; fA[mf][ks][2] = v0.z; fA[mf][ks][3] = v0.w;
            fA[mf][ks][4] = v1.x; fA[mf][ks][5] = v1.y; fA[mf][ks][6] = v1.z; fA[mf][ks][7] = v1.w;
        }
    }

    short8 Ah[2][2], Al[2][2];
    #pragma unroll
    for (int mf = 0; mf < 2; ++mf)
        #pragma unroll
        for (int ks = 0; ks < 2; ++ks)
            #pragma unroll
            for (int j = 0; j < 8; ++j) {
                float x = fA[mf][ks][j];
                unsigned short h = f2bf(x);
                Ah[mf][ks][j] = (short)h;
                Al[mf][ks][j] = (short)f2bf(x - bf2f(h));
            }

    floatx4 C[2][8];
    #pragma unroll
    for (int mf = 0; mf < 2; ++mf)
        #pragma unroll
        for (int nf = 0; nf < 8; ++nf) C[mf][nf] = (floatx4)0.f;

    #pragma unroll
    for (int ks = 0; ks < 2; ++ks) {
        #pragma unroll
        for (int nf = 0; nf < 8; ++nf) {
            const float* wp = w + (size_t)(nf * 16 + L) * DIM + ks * 32 + q * 8;
            float4 u0 = *(const float4*)(wp);
            float4 u1 = *(const float4*)(wp + 4);
            float bw[8] = {u0.x, u0.y, u0.z, u0.w, u1.x, u1.y, u1.z, u1.w};
            short8 Bh, Bl;
            #pragma unroll
            for (int j = 0; j < 8; ++j) {
                unsigned short h = f2bf(bw[j]);
                Bh[j] = (short)h;
                Bl[j] = (short)f2bf(bw[j] - bf2f(h));
            }
            #pragma unroll
            for (int mf = 0; mf < 2; ++mf) {
                C[mf][nf] = __builtin_amdgcn_mfma_f32_16x16x32_bf16(Ah[mf][ks], Bh, C[mf][nf], 0, 0, 0);
                C[mf][nf] = __builtin_amdgcn_mfma_f32_16x16x32_bf16(Al[mf][ks], Bh, C[mf][nf], 0, 0, 0);
                C[mf][nf] = __builtin_amdgcn_mfma_f32_16x16x32_bf16(Ah[mf][ks], Bl, C[mf][nf], 0, 0, 0);
            }
        }
    }

    // ---- pq from exact fp32 C . alpha (row = mf*16+q*4+r, col = nf*16+L)
    float alf[8];
    #pragma unroll
    for (int nf = 0; nf < 8; ++nf) alf[nf] = alpha[nf * 16 + L];
    #pragma unroll
    for (int mf = 0; mf < 2; ++mf) {
        #pragma unroll
        for (int r = 0; r < 4; ++r) {
            float s = 0.f;
            #pragma unroll
            for (int nf = 0; nf < 8; ++nf) s = fmaf(C[mf][nf][r], alf[nf], s);
            s += __shfl_xor(s, 1); s += __shfl_xor(s, 2);
            s += __shfl_xor(s, 4); s += __shfl_xor(s, 8);
            if (L == 0)
                pq[base + mf * 16 + q * 4 + r] = make_float2(__expf(s), __expf(0.2f * s));
        }
    }

    // ---- transpose via per-wave LDS slice, store h_t[b][n][o] coalesced
    __shared__ unsigned short T[4][128 * 34];
    #pragma unroll
    for (int mf = 0; mf < 2; ++mf)
        #pragma unroll
        for (int nf = 0; nf < 8; ++nf)
            #pragma unroll
            for (int r = 0; r < 4; ++r)
                T[wid][(nf * 16 + L) * 34 + mf * 16 + q * 4 + r] = f2bf(C[mf][nf][r]);
    __syncthreads();
    unsigned short* htb = h_t + (size_t)b * KOUT * N_OPE;
    #pragma unroll 4
    for (int t = 0; t < 32; ++t) {
        int n = t * 4 + q;
        ushort2 v = *(const ushort2*)&T[wid][n * 34 + 2 * L];
        *(ushort2*)(htb + (size_t)n * N_OPE + o0w + 2 * L) = v;
    }
}

// ---------------- kernel 2: h_res -> out (3-term bf16 MFMA), attn_mac ----------------
__global__ __launch_bounds__(256, 2) void k_mac(const float* __restrict__ feat,
        const float* __restrict__ w, const float* __restrict__ wa,
        float* __restrict__ out, float* __restrict__ attn)
{
    int wid = threadIdx.x >> 6, lane = threadIdx.x & 63;
    int L = lane & 15, q = lane >> 4;
    int base = blockIdx.x * 128 + wid * 32;            // row base (32768 rows total)

    float fA[2][2][8];
    #pragma unroll
    for (int mf = 0; mf < 2; ++mf) {
        const float* fr = feat + (size_t)(base + mf * 16 + L) * DIM + q * 8;
        #pragma unroll
        for (int ks = 0; ks < 2; ++ks) {
            float4 v0 = *(const float4*)(fr + ks * 32);
            float4 v1 = *(const float4*)(fr + ks * 32 + 4);
            fA[mf][ks][0] = v0.x; fA[mf][ks][1] = v0.y; fA[mf][ks][2] = v0.z; fA[mf][ks][3] = v0.w;
            fA[mf][ks][4] = v1.x; fA[mf][ks][5] = v1.y; fA[mf][ks][6] = v1.z; fA[mf][ks][7] = v1.w;
        }
    }

    float wav[2][8];
    #pragma unroll
    for (int ks = 0; ks < 2; ++ks) {
        float4 w0 = *(const float4*)(wa + ks * 32 + q * 8);
        float4 w1 = *(const float4*)(wa + ks * 32 + q * 8 + 4);
        wav[ks][0] = w0.x; wav[ks][1] = w0.y; wav[ks][2] = w0.z; wav[ks][3] = w0.w;
        wav[ks][4] = w1.x; wav[ks][5] = w1.y; wav[ks][6] = w1.z; wav[ks][7] = w1.w;
    }
    float part[2] = {0.f, 0.f};
    #pragma unroll
    for (int mf = 0; mf < 2; ++mf)
        #pragma unroll
        for (int ks = 0; ks < 2; ++ks)
            #pragma unroll
            for (int j = 0; j < 8; ++j)
                part[mf] = fmaf(fA[mf][ks][j], wav[ks][j], part[mf]);
    part[0] += __shfl_xor(part[0], 16); part[0] += __shfl_xor(part[0], 32);
    part[1] += __shfl_xor(part[1], 16); part[1] += __shfl_xor(part[1], 32);
    if (q == 0) {
        attn[base + L]      = part[0];
        attn[base + 16 + L] = part[1];
    }

    short8 Ah[2][2], Al[2][2];
    #pragma unroll
    for (int mf = 0; mf < 2; ++mf)
        #pragma unroll
        for (int ks = 0; ks < 2; ++ks)
            #pragma unroll
            for (int j = 0; j < 8; ++j) {
                float x = fA[mf][ks][j];
                unsigned short h = f2bf(x);
                Ah[mf][ks][j] = (short)h;
                Al[mf][ks][j] = (short)f2bf(x - bf2f(h));
            }

    floatx4 C[2][8];
    #pragma unroll
    for (int mf = 0; mf < 2; ++mf)
        #pragma unroll
        for (int nf = 0; nf < 8; ++nf) C[mf][nf] = (floatx4)0.f;

    #pragma unroll
    for (int ks = 0; ks < 2; ++ks) {
        #pragma unroll
        for (int nf = 0; nf < 8; ++nf) {
            const float* wp = w + (size_t)(nf * 16 + L) * DIM + ks * 32 + q * 8;
            float4 u0 = *(const float4*)(wp);
            float4 u1 = *(const float4*)(wp + 4);
            float bw[8] = {u0.x, u0.y, u0.z, u0.w, u1.x, u1.y, u1.z, u1.w};
            short8 Bh, Bl;
            #pragma unroll
            for (int j = 0; j < 8; ++j) {
                unsigned short h = f2bf(bw[j]);
                Bh[j] = (short)h;
                Bl[j] = (short)f2bf(bw[j] - bf2f(h));
            }
            #pragma unroll
            for (int mf = 0; mf < 2; ++mf) {
                C[mf][nf] = __builtin_amdgcn_mfma_f32_16x16x32_bf16(Ah[mf][ks], Bh, C[mf][nf], 0, 0, 0);
                C[mf][nf] = __builtin_amdgcn_mfma_f32_16x16x32_bf16(Al[mf][ks], Bh, C[mf][nf], 0, 0, 0);
                C[mf][nf] = __builtin_amdgcn_mfma_f32_16x16x32_bf16(Ah[mf][ks], Bl, C[mf][nf], 0, 0, 0);
            }
        }
    }

    #pragma unroll
    for (int mf = 0; mf < 2; ++mf)
        #pragma unroll
        for (int nf = 0; nf < 8; ++nf)
            #pragma unroll
            for (int r = 0; r < 4; ++r)
                out[(size_t)(base + mf * 16 + q * 4 + r) * KOUT + nf * 16 + L] = C[mf][nf][r];
}

// ---------------- kernel 3: slim fused mask->softmax->MFMA, accumulates into out ----
// even/odd m-pairing: frag0 <-> machine m0+2L, frag1 <-> m0+2L+1 => int2 mask loads,
// each instruction covers 4 full 128B lines. No launch_bounds min (no spill pressure).
__global__ __launch_bounds__(256) void k_attn(const int* __restrict__ adj,
        const int* __restrict__ bidx,
        const unsigned short* __restrict__ h_t,
        const float2* __restrict__ pq,
        const float* __restrict__ attn_mac,
        float* __restrict__ out)
{
    int lin = blockIdx.x;                              // 1024
    int b   = 4 * (lin & 7) + ((lin >> 3) & 3);        // XCD k serves b in {4k..4k+3}
    int m0  = (lin >> 5) * 32;
    int t = threadIdx.x, wv = t >> 6, lane = t & 63;
    int L = lane & 15, q = lane >> 4;

    const int* adjt = adj + (size_t)bidx[b] * (N_OPE * N_MAC);
    const unsigned short* htb = h_t + (size_t)b * KOUT * N_OPE;
    const float2* pqb = pq + (size_t)b * N_OPE;

    float2 amv = *(const float2*)(attn_mac + (size_t)b * N_MAC + m0 + 2 * L);
    float pM0 = __expf(amv.x), qM0 = __expf(0.2f * amv.x);
    float pM1 = __expf(amv.y), qM1 = __expf(0.2f * amv.y);

    floatx4 C0[8], C1[8];
    #pragma unroll
    for (int i = 0; i < 8; ++i) { C0[i] = (floatx4)0.f; C1[i] = (floatx4)0.f; }
    float den0 = 0.f, den1 = 0.f;

    int oBeg = wv * (N_OPE / 4);
    for (int o0 = oBeg; o0 < oBeg + N_OPE / 4; o0 += 32) {
        int ob = o0 + q * 8;
        float4 pv0 = *(const float4*)(pqb + ob);
        float4 pv1 = *(const float4*)(pqb + ob + 2);
        float4 pv2 = *(const float4*)(pqb + ob + 4);
        float4 pv3 = *(const float4*)(pqb + ob + 6);
        float pA[8] = {pv0.x, pv0.z, pv1.x, pv1.z, pv2.x, pv2.z, pv3.x, pv3.z};
        float qA[8] = {pv0.y, pv0.w, pv1.y, pv1.w, pv2.y, pv2.w, pv3.y, pv3.w};

        int2 mk[8];
        #pragma unroll
        for (int j = 0; j < 8; ++j)
            mk[j] = *(const int2*)(adjt + (size_t)(ob + j) * N_MAC + m0 + 2 * L);

        short8 Bf[8];
        #pragma unroll
        for (int nf = 0; nf < 8; ++nf)
            Bf[nf] = *(const short8*)(htb + (size_t)(nf * 16 + L) * N_OPE + ob);

        float w0v[8], w1v[8];
        #pragma unroll
        for (int j = 0; j < 8; ++j) {
            float tp0 = pA[j] * pM0;
            float w0 = (tp0 >= 1.0f) ? tp0 : qA[j] * qM0;
            w0 = (mk[j].x == 1) ? w0 : 0.f;
            den0 += w0; w0v[j] = w0;
            float tp1 = pA[j] * pM1;
            float w1 = (tp1 >= 1.0f) ? tp1 : qA[j] * qM1;
            w1 = (mk[j].y == 1) ? w1 : 0.f;
            den1 += w1; w1v[j] = w1;
        }
        int4 A0i, A1i;
        #pragma unroll
        for (int j2 = 0; j2 < 4; ++j2) {
            unsigned lo0 = __builtin_bit_cast(unsigned, w0v[2 * j2])     + 0x8000u;
            unsigned hi0 = __builtin_bit_cast(unsigned, w0v[2 * j2 + 1]) + 0x8000u;
            ((unsigned*)&A0i)[j2] = __builtin_amdgcn_perm(hi0, lo0, 0x07060302u);
            unsigned lo1 = __builtin_bit_cast(unsigned, w1v[2 * j2])     + 0x8000u;
            unsigned hi1 = __builtin_bit_cast(unsigned, w1v[2 * j2 + 1]) + 0x8000u;
            ((unsigned*)&A1i)[j2] = __builtin_amdgcn_perm(hi1, lo1, 0x07060302u);
        }
        short8 A0 = __builtin_bit_cast(short8, A0i);
        short8 A1 = __builtin_bit_cast(short8, A1i);

        #pragma unroll
        for (int nf = 0; nf < 8; ++nf) {
            C0[nf] = __builtin_amdgcn_mfma_f32_16x16x32_bf16(A0, Bf[nf], C0[nf], 0, 0, 0);
            C1[nf] = __builtin_amdgcn_mfma_f32_16x16x32_bf16(A1, Bf[nf], C1[nf], 0, 0, 0);
        }
    }

    den0 += __shfl_xor(den0, 16); den0 += __shfl_xor(den0, 32);
    den1 += __shfl_xor(den1, 16); den1 += __shfl_xor(den1, 32);

    __shared__ float buf0[32 * 132];
    __shared__ float buf1[32 * 132];
    __shared__ float DS[4][32];
    if (q == 0) { DS[wv][L] = den0; DS[wv][16 + L] = den1; }

    if (wv == 0 || wv == 2) {
        float* bp = (wv == 0) ? buf0 : buf1;
        #pragma unroll
        for (int mf = 0; mf < 2; ++mf) {
            const floatx4* Cf = mf ? C1 : C0;
            #pragma unroll
            for (int nf = 0; nf < 8; ++nf)
                #pragma unroll
                for (int r = 0; r < 4; ++r)
                    bp[(mf * 16 + q * 4 + r) * 132 + nf * 16 + L] = Cf[nf][r];
        }
    }
    __syncthreads();
    if (wv == 1 || wv == 3) {
        float* bp = (wv == 1) ? buf0 : buf1;
        #pragma unroll
        for (int mf = 0; mf < 2; ++mf) {
            const floatx4* Cf = mf ? C1 : C0;
            #pragma unroll
            for (int nf = 0; nf < 8; ++nf)
                #pragma unroll
                for (int r = 0; r < 4; ++r)
                    bp[(mf * 16 + q * 4 + r) * 132 + nf * 16 + L] += Cf[nf][r];
        }
    }
    __syncthreads();

    // epilogue: wave covers its 2 n-frags; machine m = m0 + 2*fragrow + mf
    #pragma unroll
    for (int mf = 0; mf < 2; ++mf) {
        #pragma unroll
        for (int r = 0; r < 4; ++r) {
            int fragrow = q * 4 + r;
            int m = m0 + 2 * fragrow + mf;
            float inv = 1.0f / (DS[0][mf * 16 + fragrow] + DS[1][mf * 16 + fragrow]
                              + DS[2][mf * 16 + fragrow] + DS[3][mf * 16 + fragrow]);
            size_t obase = ((size_t)b * N_MAC + m) * KOUT;
            #pragma unroll
            for (int nfl = 0; nfl < 2; ++nfl) {
                int col = (wv * 2 + nfl) * 16 + L;
                float num = buf0[(mf * 16 + fragrow) * 132 + col]
                          + buf1[(mf * 16 + fragrow) * 132 + col];
                out[obase + col] = num * inv + out[obase + col];
            }
        }
    }
}

extern "C" void kernel_launch(void* const* d_in, const int* in_sizes, int n_in,
                              void* d_out, int out_size, void* d_ws, size_t ws_size,
                              hipStream_t stream) {
    const int*   adj       = (const int*)d_in[0];
    const int*   bidx      = (const int*)d_in[1];
    const float* feat_ope  = (const float*)d_in[2];
    const float* feat_mac  = (const float*)d_in[3];
    const float* ope_w     = (const float*)d_in[4];
    const float* mac_w     = (const float*)d_in[5];
    const float* ope_alpha = (const float*)d_in[6];
    const float* mac_alpha = (const float*)d_in[7];
    const float* res_w     = (const float*)d_in[8];
    float* out = (float*)d_out;

    char* ws = (char*)d_ws;
    unsigned short* h_t = (unsigned short*)ws;                           // 16 MiB
    float2* pq          = (float2*)(ws + (size_t)(16 << 20));            // 512 KiB
    float*  attn_mac    = (float*)(ws + (size_t)(16 << 20) + (512 << 10)); // 128 KiB
    float*  wa          = (float*)(ws + (size_t)(16 << 20) + (640 << 10)); // 256 B

    k_wa<<<1, 64, 0, stream>>>(mac_w, mac_alpha, wa);
    k_ope<<<512, 256, 0, stream>>>(feat_ope, ope_w, ope_alpha, h_t, pq);
    k_mac<<<256, 256, 0, stream>>>(feat_mac, res_w, wa, out, attn_mac);
    k_attn<<<1024, 256, 0, stream>>>(adj, bidx, h_t, pq, attn_mac, out);
}

// Round 5
// 694.973 us; speedup vs baseline: 1.0656x; 1.0656x over previous
//
#include <hip/hip_runtime.h>

#define N_OPE 2048
#define N_MAC 1024
#define DIM   64
#define KOUT  128
#define NB    32

typedef __attribute__((ext_vector_type(8))) short short8;
typedef __attribute__((ext_vector_type(4))) float floatx4;

static __device__ __forceinline__ unsigned short f2bf(float f) {
    unsigned int u = __builtin_bit_cast(unsigned int, f);
    u += 0x7fffu + ((u >> 16) & 1u);   // round-to-nearest-even
    return (unsigned short)(u >> 16);
}
static __device__ __forceinline__ float bf2f(unsigned short h) {
    unsigned int u = ((unsigned int)h) << 16;
    return __builtin_bit_cast(float, u);
}

// ---------------- kernel 1: h_ope via 3-term bf16 MFMA -> h_f (FRAGMENT-MAJOR bf16),
//                  plus pq[o] = (exp(attn_ope), exp(0.2*attn_ope)) from exact C.alpha ----
// h_f[b][oc][nf][lane] holds the exact short8 k_attn's lane wants: both k_ope stores
// and k_attn loads are single-segment 1KiB/instr dwordx4.
__global__ __launch_bounds__(256, 2) void k_ope(const float* __restrict__ feat,
        const float* __restrict__ w, const float* __restrict__ alpha,
        unsigned short* __restrict__ h_f, float2* __restrict__ pq)
{
    int wid = threadIdx.x >> 6, lane = threadIdx.x & 63;
    int L = lane & 15, q = lane >> 4;
    int base = blockIdx.x * 128 + wid * 32;           // row base for this wave
    int b = base >> 11;                                // rows per batch = 2048
    int o0w = base & (N_OPE - 1);

    float fA[2][2][8];                                 // [mf][ks][j]
    #pragma unroll
    for (int mf = 0; mf < 2; ++mf) {
        const float* fr = feat + (size_t)(base + mf * 16 + L) * DIM + q * 8;
        #pragma unroll
        for (int ks = 0; ks < 2; ++ks) {
            float4 v0 = *(const float4*)(fr + ks * 32);
            float4 v1 = *(const float4*)(fr + ks * 32 + 4);
            fA[mf][ks][0] = v0.x; fA[mf][ks][1] = v0.y; fA[mf][ks][2] = v0.z; fA[mf][ks][3] = v0.w;
            fA[mf][ks][4] = v1.x; fA[mf][ks][5] = v1.y; fA[mf][ks][6] = v1.z; fA[mf][ks][7] = v1.w;
        }
    }

    short8 Ah[2][2], Al[2][2];
    #pragma unroll
    for (int mf = 0; mf < 2; ++mf)
        #pragma unroll
        for (int ks = 0; ks < 2; ++ks)
            #pragma unroll
            for (int j = 0; j < 8; ++j) {
                float x = fA[mf][ks][j];
                unsigned short h = f2bf(x);
                Ah[mf][ks][j] = (short)h;
                Al[mf][ks][j] = (short)f2bf(x - bf2f(h));
            }

    floatx4 C[2][8];
    #pragma unroll
    for (int mf = 0; mf < 2; ++mf)
        #pragma unroll
        for (int nf = 0; nf < 8; ++nf) C[mf][nf] = (floatx4)0.f;

    #pragma unroll
    for (int ks = 0; ks < 2; ++ks) {
        #pragma unroll
        for (int nf = 0; nf < 8; ++nf) {
            const float* wp = w + (size_t)(nf * 16 + L) * DIM + ks * 32 + q * 8;
            float4 u0 = *(const float4*)(wp);
            float4 u1 = *(const float4*)(wp + 4);
            float bw[8] = {u0.x, u0.y, u0.z, u0.w, u1.x, u1.y, u1.z, u1.w};
            short8 Bh, Bl;
            #pragma unroll
            for (int j = 0; j < 8; ++j) {
                unsigned short h = f2bf(bw[j]);
                Bh[j] = (short)h;
                Bl[j] = (short)f2bf(bw[j] - bf2f(h));
            }
            #pragma unroll
            for (int mf = 0; mf < 2; ++mf) {
                C[mf][nf] = __builtin_amdgcn_mfma_f32_16x16x32_bf16(Ah[mf][ks], Bh, C[mf][nf], 0, 0, 0);
                C[mf][nf] = __builtin_amdgcn_mfma_f32_16x16x32_bf16(Al[mf][ks], Bh, C[mf][nf], 0, 0, 0);
                C[mf][nf] = __builtin_amdgcn_mfma_f32_16x16x32_bf16(Ah[mf][ks], Bl, C[mf][nf], 0, 0, 0);
            }
        }
    }

    // ---- pq from exact fp32 C . alpha (row = mf*16+q*4+r, col = nf*16+L)
    float alf[8];
    #pragma unroll
    for (int nf = 0; nf < 8; ++nf) alf[nf] = alpha[nf * 16 + L];
    #pragma unroll
    for (int mf = 0; mf < 2; ++mf) {
        #pragma unroll
        for (int r = 0; r < 4; ++r) {
            float s = 0.f;
            #pragma unroll
            for (int nf = 0; nf < 8; ++nf) s = fmaf(C[mf][nf][r], alf[nf], s);
            s += __shfl_xor(s, 1); s += __shfl_xor(s, 2);
            s += __shfl_xor(s, 4); s += __shfl_xor(s, 8);
            if (L == 0)
                pq[base + mf * 16 + q * 4 + r] = make_float2(__expf(s), __expf(0.2f * s));
        }
    }

    // ---- transpose via per-wave LDS slice (stride 40 shorts => 16B-aligned b128 reads)
    __shared__ unsigned short T[4][128 * 40];
    #pragma unroll
    for (int mf = 0; mf < 2; ++mf)
        #pragma unroll
        for (int nf = 0; nf < 8; ++nf)
            #pragma unroll
            for (int r = 0; r < 4; ++r)
                T[wid][(nf * 16 + L) * 40 + mf * 16 + q * 4 + r] = f2bf(C[mf][nf][r]);
    __syncthreads();

    // ---- fragment-major store: lane (L,q) emits exactly k_attn lane's short8
    int oc = o0w >> 5;
    unsigned short* dst = h_f + ((((size_t)b * 64 + oc) * 8) * 64 + lane) * 8;
    #pragma unroll
    for (int nf = 0; nf < 8; ++nf) {
        short8 v = *(const short8*)&T[wid][(nf * 16 + L) * 40 + q * 8];
        *(short8*)(dst + (size_t)nf * 512) = v;
    }
}

// ---------------- kernel 2: fully fused mask->softmax->MFMA + h_res ----------------
// 4 waves, 4-way K-split, even/odd m-pairing (int2 masks), fragment-major B loads.
__global__ __launch_bounds__(256) void k_attn(const int* __restrict__ adj,
        const int* __restrict__ bidx,
        const unsigned short* __restrict__ h_f,
        const float2* __restrict__ pq,
        const float* __restrict__ feat_mac,
        const float* __restrict__ mac_w, const float* __restrict__ mac_alpha,
        const float* __restrict__ res_w,
        float* __restrict__ out)
{
    int b  = blockIdx.y;
    int m0 = blockIdx.x * 32;
    int t = threadIdx.x, wv = t >> 6, lane = t & 63;
    int L = lane & 15, q = lane >> 4;

    __shared__ float buf0[32 * 132];
    __shared__ float buf1[32 * 132];
    __shared__ float waS[64];
    __shared__ float amS[32];
    __shared__ float DS[4][32];

    // ---- wa[d] = sum_n mac_w[n][d]*mac_alpha[n]
    {
        int d = t & 63, seg = t >> 6;
        float p = 0.f;
        #pragma unroll 8
        for (int n = seg * 32; n < seg * 32 + 32; ++n)
            p = fmaf(mac_w[n * DIM + d], mac_alpha[n], p);
        buf0[seg * 64 + d] = p;
    }
    __syncthreads();
    if (t < 64) waS[t] = buf0[t] + buf0[64 + t] + buf0[128 + t] + buf0[192 + t];
    __syncthreads();
    // ---- am[m] = feat_mac[b][m0+m] . waS
    {
        int row = t & 31, seg = t >> 5;
        const float* fr = feat_mac + ((size_t)b * N_MAC + m0 + row) * DIM + seg * 8;
        float p = 0.f;
        #pragma unroll
        for (int k = 0; k < 8; ++k) p = fmaf(fr[k], waS[seg * 8 + k], p);
        buf1[seg * 32 + row] = p;
    }
    __syncthreads();
    if (t < 32) {
        float s = 0.f;
        #pragma unroll
        for (int sg = 0; sg < 8; ++sg) s += buf1[sg * 32 + t];
        amS[t] = s;
    }
    __syncthreads();

    float2 amv = *(const float2*)&amS[2 * L];          // frag0: m0+2L, frag1: m0+2L+1
    float pM0 = __expf(amv.x), qM0 = __expf(0.2f * amv.x);
    float pM1 = __expf(amv.y), qM1 = __expf(0.2f * amv.y);

    const int* adjt = adj + (size_t)bidx[b] * (N_OPE * N_MAC);
    const unsigned short* hfb = h_f + (size_t)b * (64 * 8 * 64 * 8);
    const float2* pqb = pq + (size_t)b * N_OPE;

    floatx4 C0[8], C1[8];
    #pragma unroll
    for (int i = 0; i < 8; ++i) { C0[i] = (floatx4)0.f; C1[i] = (floatx4)0.f; }
    float den0 = 0.f, den1 = 0.f;

    int oBeg = wv * (N_OPE / 4);
    for (int o0 = oBeg; o0 < oBeg + N_OPE / 4; o0 += 32) {
        int ob = o0 + q * 8;
        float4 pv0 = *(const float4*)(pqb + ob);
        float4 pv1 = *(const float4*)(pqb + ob + 2);
        float4 pv2 = *(const float4*)(pqb + ob + 4);
        float4 pv3 = *(const float4*)(pqb + ob + 6);
        float pA[8] = {pv0.x, pv0.z, pv1.x, pv1.z, pv2.x, pv2.z, pv3.x, pv3.z};
        float qA[8] = {pv0.y, pv0.w, pv1.y, pv1.w, pv2.y, pv2.w, pv3.y, pv3.w};

        int2 mk[8];
        #pragma unroll
        for (int j = 0; j < 8; ++j)
            mk[j] = *(const int2*)(adjt + (size_t)(ob + j) * N_MAC + m0 + 2 * L);

        const unsigned short* fp = hfb + (((size_t)(o0 >> 5) * 8) * 64 + lane) * 8;
        short8 Bf[8];
        #pragma unroll
        for (int nf = 0; nf < 8; ++nf)
            Bf[nf] = *(const short8*)(fp + (size_t)nf * 512);

        float w0v[8], w1v[8];
        #pragma unroll
        for (int j = 0; j < 8; ++j) {
            float tp0 = pA[j] * pM0;
            float w0 = (tp0 >= 1.0f) ? tp0 : qA[j] * qM0;
            w0 = (mk[j].x == 1) ? w0 : 0.f;
            den0 += w0; w0v[j] = w0;
            float tp1 = pA[j] * pM1;
            float w1 = (tp1 >= 1.0f) ? tp1 : qA[j] * qM1;
            w1 = (mk[j].y == 1) ? w1 : 0.f;
            den1 += w1; w1v[j] = w1;
        }
        int4 A0i, A1i;
        #pragma unroll
        for (int j2 = 0; j2 < 4; ++j2) {
            unsigned lo0 = __builtin_bit_cast(unsigned, w0v[2 * j2])     + 0x8000u;
            unsigned hi0 = __builtin_bit_cast(unsigned, w0v[2 * j2 + 1]) + 0x8000u;
            ((unsigned*)&A0i)[j2] = __builtin_amdgcn_perm(hi0, lo0, 0x07060302u);
            unsigned lo1 = __builtin_bit_cast(unsigned, w1v[2 * j2])     + 0x8000u;
            unsigned hi1 = __builtin_bit_cast(unsigned, w1v[2 * j2 + 1]) + 0x8000u;
            ((unsigned*)&A1i)[j2] = __builtin_amdgcn_perm(hi1, lo1, 0x07060302u);
        }
        short8 A0 = __builtin_bit_cast(short8, A0i);
        short8 A1 = __builtin_bit_cast(short8, A1i);

        #pragma unroll
        for (int nf = 0; nf < 8; ++nf) {
            C0[nf] = __builtin_amdgcn_mfma_f32_16x16x32_bf16(A0, Bf[nf], C0[nf], 0, 0, 0);
            C1[nf] = __builtin_amdgcn_mfma_f32_16x16x32_bf16(A1, Bf[nf], C1[nf], 0, 0, 0);
        }
    }

    den0 += __shfl_xor(den0, 16); den0 += __shfl_xor(den0, 32);
    den1 += __shfl_xor(den1, 16); den1 += __shfl_xor(den1, 32);
    if (q == 0) { DS[wv][L] = den0; DS[wv][16 + L] = den1; }

    // ---- cross-wave C reduction
    if (wv == 0 || wv == 2) {
        float* bp = (wv == 0) ? buf0 : buf1;
        #pragma unroll
        for (int mf = 0; mf < 2; ++mf) {
            const floatx4* Cf = mf ? C1 : C0;
            #pragma unroll
            for (int nf = 0; nf < 8; ++nf)
                #pragma unroll
                for (int r = 0; r < 4; ++r)
                    bp[(mf * 16 + q * 4 + r) * 132 + nf * 16 + L] = Cf[nf][r];
        }
    }
    __syncthreads();
    if (wv == 1 || wv == 3) {
        float* bp = (wv == 1) ? buf0 : buf1;
        #pragma unroll
        for (int mf = 0; mf < 2; ++mf) {
            const floatx4* Cf = mf ? C1 : C0;
            #pragma unroll
            for (int nf = 0; nf < 8; ++nf)
                #pragma unroll
                for (int r = 0; r < 4; ++r)
                    bp[(mf * 16 + q * 4 + r) * 132 + nf * 16 + L] += Cf[nf][r];
        }
    }
    __syncthreads();

    // ---- inline h_res (3-term split MFMA); machine m = m0 + 2L + mf for A-frag mf
    float fA[2][2][8];
    #pragma unroll
    for (int mf = 0; mf < 2; ++mf) {
        const float* fr = feat_mac + ((size_t)b * N_MAC + m0 + 2 * L + mf) * DIM + q * 8;
        #pragma unroll
        for (int ks = 0; ks < 2; ++ks) {
            float4 v0 = *(const float4*)(fr + ks * 32);
            float4 v1 = *(const float4*)(fr + ks * 32 + 4);
            fA[mf][ks][0] = v0.x; fA[mf][ks][1] = v0.y; fA[mf][ks][2] = v0.z; fA[mf][ks][3] = v0.w;
            fA[mf][ks][4] = v1.x; fA[mf][ks][5] = v1.y; fA[mf][ks][6] = v1.z; fA[mf][ks][7] = v1.w;
        }
    }
    short8 Ah[2][2], Al[2][2];
    #pragma unroll
    for (int mf = 0; mf < 2; ++mf)
        #pragma unroll
        for (int ks = 0; ks < 2; ++ks)
            #pragma unroll
            for (int j = 0; j < 8; ++j) {
                float x = fA[mf][ks][j];
                unsigned short h = f2bf(x);
                Ah[mf][ks][j] = (short)h;
                Al[mf][ks][j] = (short)f2bf(x - bf2f(h));
            }
    floatx4 R[2][2];
    R[0][0] = (floatx4)0.f; R[0][1] = (floatx4)0.f;
    R[1][0] = (floatx4)0.f; R[1][1] = (floatx4)0.f;
    #pragma unroll
    for (int ks = 0; ks < 2; ++ks) {
        #pragma unroll
        for (int nfl = 0; nfl < 2; ++nfl) {
            const float* wp = res_w + (size_t)((wv * 2 + nfl) * 16 + L) * DIM + ks * 32 + q * 8;
            float4 u0 = *(const float4*)(wp);
            float4 u1 = *(const float4*)(wp + 4);
            float bw[8] = {u0.x, u0.y, u0.z, u0.w, u1.x, u1.y, u1.z, u1.w};
            short8 Bh, Bl;
            #pragma unroll
            for (int j = 0; j < 8; ++j) {
                unsigned short h = f2bf(bw[j]);
                Bh[j] = (short)h;
                Bl[j] = (short)f2bf(bw[j] - bf2f(h));
            }
            #pragma unroll
            for (int mf = 0; mf < 2; ++mf) {
                R[mf][nfl] = __builtin_amdgcn_mfma_f32_16x16x32_bf16(Ah[mf][ks], Bh, R[mf][nfl], 0, 0, 0);
                R[mf][nfl] = __builtin_amdgcn_mfma_f32_16x16x32_bf16(Al[mf][ks], Bh, R[mf][nfl], 0, 0, 0);
                R[mf][nfl] = __builtin_amdgcn_mfma_f32_16x16x32_bf16(Ah[mf][ks], Bl, R[mf][nfl], 0, 0, 0);
            }
        }
    }

    // ---- epilogue: machine m = m0 + 2*fragrow + mf; wave covers its 2 n-frags
    #pragma unroll
    for (int mf = 0; mf < 2; ++mf) {
        #pragma unroll
        for (int r = 0; r < 4; ++r) {
            int fragrow = q * 4 + r;
            int m = m0 + 2 * fragrow + mf;
            float inv = 1.0f / (DS[0][mf * 16 + fragrow] + DS[1][mf * 16 + fragrow]
                              + DS[2][mf * 16 + fragrow] + DS[3][mf * 16 + fragrow]);
            size_t obase = ((size_t)b * N_MAC + m) * KOUT;
            #pragma unroll
            for (int nfl = 0; nfl < 2; ++nfl) {
                int col = (wv * 2 + nfl) * 16 + L;
                float num = buf0[(mf * 16 + fragrow) * 132 + col]
                          + buf1[(mf * 16 + fragrow) * 132 + col];
                out[obase + col] = num * inv + R[mf][nfl][r];
            }
        }
    }
}

extern "C" void kernel_launch(void* const* d_in, const int* in_sizes, int n_in,
                              void* d_out, int out_size, void* d_ws, size_t ws_size,
                              hipStream_t stream) {
    const int*   adj       = (const int*)d_in[0];
    const int*   bidx      = (const int*)d_in[1];
    const float* feat_ope  = (const float*)d_in[2];
    const float* feat_mac  = (const float*)d_in[3];
    const float* ope_w     = (const float*)d_in[4];
    const float* mac_w     = (const float*)d_in[5];
    const float* ope_alpha = (const float*)d_in[6];
    const float* mac_alpha = (const float*)d_in[7];
    const float* res_w     = (const float*)d_in[8];
    float* out = (float*)d_out;

    char* ws = (char*)d_ws;
    unsigned short* h_f = (unsigned short*)ws;                // 16 MiB fragment-major bf16
    float2* pq          = (float2*)(ws + (size_t)(16 << 20)); // 512 KiB

    k_ope<<<512, 256, 0, stream>>>(feat_ope, ope_w, ope_alpha, h_f, pq);
    k_attn<<<dim3(N_MAC / 32, NB), 256, 0, stream>>>(adj, bidx, h_f, pq, feat_mac,
                                                     mac_w, mac_alpha, res_w, out);
}